// Round 5
// baseline (1344.498 us; speedup 1.0000x reference)
//
#include <hip/hip_runtime.h>

// WaveRNN cell, MI355X. B=32768 H=896 S=448 Q=256.
// R5 changes vs R4:
//  - All GEMMs: A staged DIRECT global->register (A frags are m-group-private;
//    the global->LDS->reg round trip was pure overhead). LDS holds only B.
//    R4 was LDS-read-throughput-bound: 128KB reads + 32KB writes per iter/CU
//    (~2200cy) vs 233cy MFMA/SIMD. New: ~270 B LDS-read per MFMA (was 682).
//  - BK=64, 3-buf B ring, UNIFORM counted staging (gate 3 gl_lds/wave/iter,
//    stages 4), unconditional stage(min(t+2,NT-1)) so compiler's static
//    vmcnt counting never branches -> its af-wait is vmcnt(3|4), no drain.
//    Manual pre-barrier wait: vmcnt(QS) at t=0, vmcnt(8+QS) after.
//  - gate: wave tile 64x96, acc[2][3][4]=96 regs, launch_bounds(1024,3).
//  - stage1/2: 4-wave 128x128 blocks, same recipe, launch_bounds(256,3).

typedef unsigned short u16;
typedef unsigned int u32;
typedef __attribute__((ext_vector_type(8))) short bf16x8;
typedef __attribute__((ext_vector_type(4))) float f32x4;

#define GAS __attribute__((address_space(1)))
#define LAS __attribute__((address_space(3)))

__device__ __forceinline__ u16 f2b(float f) {
  union { float f; u32 i; } v; v.f = f;
  return (u16)((v.i + 0x7fffu + ((v.i >> 16) & 1u)) >> 16);
}

__device__ __forceinline__ void gl_lds(const u16* g, u16* l) {
  __builtin_amdgcn_global_load_lds((const GAS void*)g, (LAS void*)l, 16, 0, 0);
}

// ---------------- f32 -> bf16 convert (prev_hidden) ----------------
__global__ void cvt_f32_bf16(const float* __restrict__ in, u16* __restrict__ outp) {
  const size_t i = ((size_t)blockIdx.x * 256 + threadIdx.x) * 4;
  const float4 v = *(const float4*)&in[i];
  ushort4 o;
  o.x = f2b(v.x); o.y = f2b(v.y); o.z = f2b(v.z); o.w = f2b(v.w);
  *(ushort4*)&outp[i] = o;
}

// --------- weight transpose, f32 row-major R x C -> bf16 C x R ---------
__device__ __forceinline__ void transpose_body(const float* __restrict__ in,
                                               u16* __restrict__ outp,
                                               int R, int C, int c0, int r0) {
  __shared__ u16 t[32][33];
  const int x = threadIdx.x, y = threadIdx.y;
  #pragma unroll
  for (int i = 0; i < 32; i += 8)
    t[y + i][x] = f2b(in[(size_t)(r0 + y + i) * C + (c0 + x)]);
  __syncthreads();
  #pragma unroll
  for (int i = 0; i < 32; i += 8)
    outp[(size_t)(c0 + y + i) * R + (r0 + x)] = t[x][y + i];
}

__global__ void transpose_f32_bf16(const float* __restrict__ in, u16* __restrict__ outp,
                                   int R, int C) {
  transpose_body(in, outp, R, C, blockIdx.x * 32, blockIdx.y * 32);
}

// merged W_O{1..4} transpose: z selects matrix; all R=448; C in {448,256}
__global__ void transpose_wo(const float* __restrict__ w1, const float* __restrict__ w2,
                             const float* __restrict__ w3, const float* __restrict__ w4,
                             u16* __restrict__ o1, u16* __restrict__ o2,
                             u16* __restrict__ o3, u16* __restrict__ o4) {
  const int z = blockIdx.z;
  const float* in = (z == 0) ? w1 : (z == 1) ? w2 : (z == 2) ? w3 : w4;
  u16* outp = (z == 0) ? o1 : (z == 1) ? o2 : (z == 2) ? o3 : o4;
  const int C = (z & 1) ? 256 : 448;
  const int c0 = blockIdx.x * 32;
  if (c0 >= C) return;
  transpose_body(in, outp, 448, C, c0, blockIdx.y * 32);
}

// ---------------- fused gate kernel: 1024 thr, 16 waves (4m x 4n) -----------
// Block tile 256 rows x (128 j-cols x 3 gates). Wave tile 64 rows x 96 cols
// (jj = 2*wn+jj2, s in 0..2; nn = jj*3+s). BK=64, NT=14.
// A: global->reg, 8 b128 loads/wave/iter (rows wm*64+mt*16+l16, col q*8).
// B: LDS only. Per buf: 24 tiles x 2KB as [nn][kh][row l16][seg] with the
// R4 XOR bank swizzle (src col pre-swizzled sc, read seg qs). 48 units of
// 1KB = 3 gl_lds per wave per iter (uniform).
__global__ __launch_bounds__(1024, 3)
void gate_kernel(const u16* __restrict__ phb, const u16* __restrict__ wrt,
                 const float* __restrict__ phf,
                 const float* __restrict__ y2, const float* __restrict__ cc,
                 const float* __restrict__ wic, const float* __restrict__ wif,
                 const float* __restrict__ bu, const float* __restrict__ br,
                 const float* __restrict__ be,
                 float* __restrict__ houtf, u16* __restrict__ hb) {
  __shared__ u16 Bl[3][24576];
  __shared__ float rowy[3 * 256];
  const int tid = threadIdx.x;
  const int lane = tid & 63, wave = tid >> 6;
  const int f = blockIdx.x;
  const int xcd = f & 7, l = f >> 3;            // 112 blocks per XCD
  const int m0 = (xcd * 16 + l / 7) * 256;      // j-inner: A-tile L2 reuse
  const int j0 = (l % 7) * 128;
  if (tid < 256) {
    const int r = m0 + tid;
    rowy[tid]       = y2[2 * r];
    rowy[256 + tid] = y2[2 * r + 1];
    rowy[512 + tid] = cc[r];
    asm volatile("s_waitcnt lgkmcnt(0)" ::: "memory");
  }
  const int wm = wave & 3, wn = wave >> 2;
  const int q = lane >> 4, l16 = lane & 15;
  const int qs = q ^ ((l16 >> 1) & 3);          // bank-swizzled read segment
  const int sr = lane >> 2;
  const int sc = ((lane & 3) ^ ((lane >> 3) & 3)) * 8;  // pre-swizzled src col

  // A base: per-lane row m0+wm*64+l16 (+mt*16), col q*8 (+t*64+kh*32)
  const u16* ag = phb + (size_t)(m0 + wm * 64 + l16) * 896 + q * 8;

  // staging: 3 units/wave; unit u = 3*wave+i; nn = u>>1, kh = u&1
  const u16* gs[3]; int lo[3];
  #pragma unroll
  for (int i = 0; i < 3; ++i) {
    const int u = 3 * wave + i, nn = u >> 1, kh = u & 1;
    const int s = nn % 3, jj = nn / 3;
    gs[i] = wrt + (size_t)(s * 896 + j0 + jj * 16 + sr) * 896 + (kh * 32 + sc);
    lo[i] = u * 512;
  }

  f32x4 acc[2][3][4];   // [jj2][s][mt]
  {
    const f32x4 z = {0.f, 0.f, 0.f, 0.f};
    #pragma unroll
    for (int a = 0; a < 2; ++a)
      #pragma unroll
      for (int s = 0; s < 3; ++s)
        #pragma unroll
        for (int m = 0; m < 4; ++m)
          acc[a][s][m] = z;
  }

  auto stage = [&](int t_) {
    u16* base = &Bl[t_ % 3][0];
    const int koff = t_ * 64;
    #pragma unroll
    for (int i = 0; i < 3; ++i) gl_lds(gs[i] + koff, base + lo[i]);
  };

  stage(0); stage(1);
  for (int t = 0; t < 14; ++t) {
    if (t == 0) asm volatile("s_waitcnt vmcnt(3)" ::: "memory");
    else        asm volatile("s_waitcnt vmcnt(11)" ::: "memory");
    __builtin_amdgcn_s_barrier();
    __builtin_amdgcn_sched_barrier(0);
    // A frags for this step (8 loads), issued before stage so the compiler's
    // af-wait is vmcnt(3) (stage stays in flight)
    bf16x8 af[2][4];
    #pragma unroll
    for (int kh = 0; kh < 2; ++kh)
      #pragma unroll
      for (int mt = 0; mt < 4; ++mt)
        af[kh][mt] = *(const bf16x8*)(ag + (size_t)mt * 16 * 896 + t * 64 + kh * 32);
    stage(t + 2 < 13 ? t + 2 : 13);   // tail re-stages same data: benign
    const u16* Sb = &Bl[t % 3][0];
    #pragma unroll
    for (int kh = 0; kh < 2; ++kh)
      #pragma unroll
      for (int jj2 = 0; jj2 < 2; ++jj2) {
        bf16x8 bf_[3];
        #pragma unroll
        for (int s = 0; s < 3; ++s) {
          const int nn = (2 * wn + jj2) * 3 + s;
          bf_[s] = *(const bf16x8*)&Sb[nn * 1024 + kh * 512 + l16 * 32 + qs * 8];
        }
        #pragma unroll
        for (int s = 0; s < 3; ++s)
          #pragma unroll
          for (int mt = 0; mt < 4; ++mt)
            acc[jj2][s][mt] = __builtin_amdgcn_mfma_f32_16x16x32_bf16(
                af[kh][mt], bf_[s], acc[jj2][s][mt], 0, 0, 0);
      }
  }

  // ---- fused epilogue: u, r, e, h; each thread owns its (u,r,e) triple
  #pragma unroll
  for (int jj2 = 0; jj2 < 2; ++jj2) {
    const int j = j0 + (2 * wn + jj2) * 16 + l16;
    float wu0, wu1, wu2, wr0, wr1, wr2, we0, we1, we2;
    if (j < 448) {
      wu0 = wic[j];       wu1 = wic[1344 + j];       wu2 = 0.f;
      wr0 = wic[448 + j]; wr1 = wic[1792 + j];       wr2 = 0.f;
      we0 = wic[896 + j]; we1 = wic[2240 + j];       we2 = 0.f;
    } else {
      const int jf = j - 448;
      wu0 = wif[jf];       wu1 = wif[1344 + jf]; wu2 = wif[2688 + jf];
      wr0 = wif[448 + jf]; wr1 = wif[1792 + jf]; wr2 = wif[3136 + jf];
      we0 = wif[896 + jf]; we1 = wif[2240 + jf]; we2 = wif[3584 + jf];
    }
    const float bju = bu[j], bjr = br[j], bje = be[j];
    #pragma unroll
    for (int mt = 0; mt < 4; ++mt) {
      const int rl = wm * 64 + mt * 16 + q * 4;
      #pragma unroll
      for (int i = 0; i < 4; ++i) {
        const float y0 = rowy[rl + i], y1 = rowy[256 + rl + i], yc = rowy[512 + rl + i];
        const float gu = acc[jj2][0][mt][i] + y0 * wu0 + y1 * wu1 + yc * wu2 + bju;
        const float gr = acc[jj2][1][mt][i] + y0 * wr0 + y1 * wr1 + yc * wr2 + bjr;
        const float uu = 1.f / (1.f + __expf(-gu));
        const float rg = 1.f / (1.f + __expf(-gr));
        const float ev = tanhf(rg * acc[jj2][2][mt][i] +
                               y0 * we0 + y1 * we1 + yc * we2 + bje);
        const size_t grow = (size_t)(m0 + rl + i);
        const float phv = phf[grow * 896 + j];
        const float h = uu * phv + (1.f - uu) * ev;
        houtf[grow * 896 + j] = h;
        hb[grow * 896 + j] = f2b(h);
      }
    }
  }
}

// ------------- 128x128 MLP GEMM, K=448 (NT=7, BK=64), A->reg, B->LDS -------
// 4 waves 2m x 2n; wave 64x64; acc[4][4]. 16 staging units = 4/wave.
__device__ __forceinline__ void mlp_gemm(const u16* __restrict__ A, int lda,
                                         const u16* __restrict__ BT, int ldb,
                                         u16 (&Bl)[3][8192],
                                         int wave, int lane, f32x4 (&acc)[4][4]) {
  const int wm = wave & 1, wn = wave >> 1;
  const int q = lane >> 4, l16 = lane & 15;
  const int qs = q ^ ((l16 >> 1) & 3);
  const int sr = lane >> 2;
  const int sc = ((lane & 3) ^ ((lane >> 3) & 3)) * 8;
  const u16* ag = A + (size_t)(wm * 64 + l16) * lda + q * 8;
  const u16* gs[4]; int lo[4];
  #pragma unroll
  for (int i = 0; i < 4; ++i) {
    const int u = 4 * wave + i, ntile = u >> 1, kh = u & 1;
    gs[i] = BT + (size_t)(ntile * 16 + sr) * ldb + (kh * 32 + sc);
    lo[i] = u * 512;
  }
  auto stage = [&](int t_) {
    u16* base = &Bl[t_ % 3][0];
    const int koff = t_ * 64;
    #pragma unroll
    for (int i = 0; i < 4; ++i) gl_lds(gs[i] + koff, base + lo[i]);
  };
  stage(0); stage(1);
  for (int t = 0; t < 7; ++t) {
    if (t == 0) asm volatile("s_waitcnt vmcnt(4)" ::: "memory");
    else        asm volatile("s_waitcnt vmcnt(12)" ::: "memory");
    __builtin_amdgcn_s_barrier();
    __builtin_amdgcn_sched_barrier(0);
    bf16x8 af[2][4];
    #pragma unroll
    for (int kh = 0; kh < 2; ++kh)
      #pragma unroll
      for (int mt = 0; mt < 4; ++mt)
        af[kh][mt] = *(const bf16x8*)(ag + (size_t)mt * 16 * lda + t * 64 + kh * 32);
    stage(t + 2 < 6 ? t + 2 : 6);     // tail re-stages same data: benign
    const u16* Sb = &Bl[t % 3][0];
    #pragma unroll
    for (int kh = 0; kh < 2; ++kh) {
      bf16x8 bf_[4];
      #pragma unroll
      for (int nf = 0; nf < 4; ++nf)
        bf_[nf] = *(const bf16x8*)&Sb[(wn * 4 + nf) * 1024 + kh * 512 + l16 * 32 + qs * 8];
      #pragma unroll
      for (int nf = 0; nf < 4; ++nf)
        #pragma unroll
        for (int mt = 0; mt < 4; ++mt)
          acc[mt][nf] = __builtin_amdgcn_mfma_f32_16x16x32_bf16(
              af[kh][mt], bf_[nf], acc[mt][nf], 0, 0, 0);
    }
  }
}

__device__ __forceinline__ void zero_acc(f32x4 (&acc)[4][4]) {
  const f32x4 z = {0.f, 0.f, 0.f, 0.f};
  #pragma unroll
  for (int mt = 0; mt < 4; ++mt)
    #pragma unroll
    for (int nt = 0; nt < 4; ++nt)
      acc[mt][nt] = z;
}

// ---------------- stage 1: T_z = relu(h_z @ W_O{1,3} + b), bf16 out ----------
// grid 2048 = 8 xcd * 64 mz_local * 4 j (swizzled; last j tile: B rows >=448
// read garbage in-ws bytes; write masked by j<448).
__global__ __launch_bounds__(256, 3)
void stage1_kernel(const u16* __restrict__ hb, const u16* __restrict__ w1t,
                   const u16* __restrict__ w3t, const float* __restrict__ b1,
                   const float* __restrict__ b3, u16* __restrict__ tc,
                   u16* __restrict__ tf) {
  __shared__ u16 Bl[3][8192];
  const int tid = threadIdx.x, lane = tid & 63, wave = tid >> 6;
  const int f = blockIdx.x;
  const int xcd = f & 7, l = f >> 3;          // l in [0,256)
  const int mz = xcd * 64 + (l >> 2);         // (m,z) pair, 512 total
  const int z = mz >> 8;
  const int m0 = (mz & 255) * 128, n0 = (l & 3) * 128;
  const u16* A = hb + (size_t)m0 * 896 + z * 448;
  const u16* BT = (z ? w3t : w1t) + (size_t)n0 * 448;
  const float* bias = z ? b3 : b1;
  u16* T = z ? tf : tc;
  const int wm = wave & 1, wn = wave >> 1, q = lane >> 4, l16 = lane & 15;
  f32x4 acc[4][4];
  zero_acc(acc);
  mlp_gemm(A, 896, BT, 448, Bl, wave, lane, acc);
  #pragma unroll
  for (int nf = 0; nf < 4; ++nf) {
    const int j = n0 + wn * 64 + nf * 16 + l16;
    if (j < 448) {
      const float bv = bias[j];
      #pragma unroll
      for (int mt = 0; mt < 4; ++mt)
        #pragma unroll
        for (int i = 0; i < 4; ++i) {
          const size_t row = (size_t)(m0 + wm * 64 + mt * 16 + q * 4 + i);
          T[row * 448 + j] = f2b(fmaxf(acc[mt][nf][i] + bv, 0.f));
        }
    }
  }
}

// ---------------- stage 2: out_z = T_z @ W_O{2,4} + b, f32 out ----------------
// grid 1024 = 8 xcd * 64 mz_local * 2 j (swizzled)
__global__ __launch_bounds__(256, 3)
void stage2_kernel(const u16* __restrict__ tc, const u16* __restrict__ tf,
                   const u16* __restrict__ w2t, const u16* __restrict__ w4t,
                   const float* __restrict__ b2_, const float* __restrict__ b4,
                   float* __restrict__ out) {
  __shared__ u16 Bl[3][8192];
  const int tid = threadIdx.x, lane = tid & 63, wave = tid >> 6;
  const int f = blockIdx.x;
  const int xcd = f & 7, l = f >> 3;          // l in [0,128)
  const int mz = xcd * 64 + (l >> 1);
  const int z = mz >> 8;
  const int m0 = (mz & 255) * 128, n0 = (l & 1) * 128;
  const u16* A = (z ? tf : tc) + (size_t)m0 * 448;
  const u16* BT = (z ? w4t : w2t) + (size_t)n0 * 448;
  const float* bias = z ? b4 : b2_;
  float* O = out + (size_t)z * 32768 * 256;
  const int wm = wave & 1, wn = wave >> 1, q = lane >> 4, l16 = lane & 15;
  f32x4 acc[4][4];
  zero_acc(acc);
  mlp_gemm(A, 448, BT, 448, Bl, wave, lane, acc);
  #pragma unroll
  for (int nf = 0; nf < 4; ++nf) {
    const int j = n0 + wn * 64 + nf * 16 + l16;  // always < 256
    const float bv = bias[j];
    #pragma unroll
    for (int mt = 0; mt < 4; ++mt)
      #pragma unroll
      for (int i = 0; i < 4; ++i) {
        const size_t row = (size_t)(m0 + wm * 64 + mt * 16 + q * 4 + i);
        O[row * 256 + j] = acc[mt][nf][i] + bv;
      }
  }
}

// ---------------- host launch ----------------
extern "C" void kernel_launch(void* const* d_in, const int* in_sizes, int n_in,
                              void* d_out, int out_size, void* d_ws, size_t ws_size,
                              hipStream_t stream) {
  const float* y2   = (const float*)d_in[0];   // prev_y (B,2)
  const float* ph   = (const float*)d_in[1];   // prev_hidden (B,896)
  const float* cc   = (const float*)d_in[2];   // current_coarse (B,1)
  const float* W_R  = (const float*)d_in[3];   // (896, 2688)
  const float* W_Ic = (const float*)d_in[4];   // (2, 1344)
  const float* W_If = (const float*)d_in[5];   // (3, 1344)
  const float* W_O1 = (const float*)d_in[6];   // (448,448)
  const float* b_O1 = (const float*)d_in[7];
  const float* W_O2 = (const float*)d_in[8];   // (448,256)
  const float* b_O2 = (const float*)d_in[9];
  const float* W_O3 = (const float*)d_in[10];
  const float* b_O3 = (const float*)d_in[11];
  const float* W_O4 = (const float*)d_in[12];
  const float* b_O4 = (const float*)d_in[13];
  const float* bu   = (const float*)d_in[14];
  const float* br   = (const float*)d_in[15];
  const float* be   = (const float*)d_in[16];
  float* out = (float*)d_out;
  u16* ws  = (u16*)d_ws;

  // workspace layout (u16 elements), all offsets multiples of 8 (16B aligned)
  u16* WRT = ws;                               // 2688*896      = 2,408,448
  u16* W1T = WRT + (size_t)2688 * 896;         // 448*448
  u16* W2T = W1T + 448 * 448;                  // 256*448
  u16* W3T = W2T + 256 * 448;                  // 448*448
  u16* W4T = W3T + 448 * 448;                  // 256*448
  u16* phb = W4T + 256 * 448;                  // 32768*896 bf16
  u16* hb  = phb + (size_t)32768 * 896;        // 32768*896 bf16
  // Tc/Tf alias phb (dead after gate_kernel): 2 x 32768*448
  u16* Tc  = phb;
  u16* Tf  = phb + (size_t)32768 * 448;
  float* hidf = out + (size_t)2 * 32768 * 256; // hidden (output 2) in d_out

  dim3 tb(32, 8);
  cvt_f32_bf16<<<28672, 256, 0, stream>>>(ph, phb);
  transpose_f32_bf16<<<dim3(2688 / 32, 896 / 32), tb, 0, stream>>>(W_R, WRT, 896, 2688);
  transpose_wo<<<dim3(14, 14, 4), tb, 0, stream>>>(W_O1, W_O2, W_O3, W_O4,
                                                   W1T, W2T, W3T, W4T);

  gate_kernel<<<896, 1024, 0, stream>>>(phb, WRT, ph, y2, cc, W_Ic, W_If,
                                        bu, br, be, hidf, hb);
  stage1_kernel<<<2048, 256, 0, stream>>>(hb, W1T, W3T, b_O1, b_O3, Tc, Tf);
  stage2_kernel<<<1024, 256, 0, stream>>>(Tc, Tf, W2T, W4T, b_O2, b_O4, out);
}

// Round 6
// 797.458 us; speedup vs baseline: 1.6860x; 1.6860x over previous
//
#include <hip/hip_runtime.h>

// WaveRNN cell, MI355X. B=32768 H=896 S=448 Q=256.
// R6 changes vs R5 (which spilled: acc 96 + 32 af > 128-reg cap at 4 w/SIMD ->
// 2.2GB scratch traffic, gate 967us):
//  - gate back to acc[2][3][2]=48 (R4's proven budget) but KEEPS R5's A-to-reg
//    + B-only LDS 3-ring: 512-thr blocks, 8 waves 2m x 4n, block 64 x 384.
//    B staging = 24 x 1KB units = 3/wave UNIFORM; LDS 74.5KB -> 2 blocks/CU.
//    Per iter LDS = 24KB W + 48KB R (R4: 160KB), A 16KB via VMEM (overlaps).
//  - vmcnt(3) top-of-iter (in-order vmem retirement + 3 newer loads => buf
//    ready); explicit vmcnt(0) after K-loops so no gl_lds lands after the
//    block's LDS is reallocated.
//  - stage1/2: R5 mlp_gemm kept (fits 170-reg cap at (256,3)).

typedef unsigned short u16;
typedef unsigned int u32;
typedef __attribute__((ext_vector_type(8))) short bf16x8;
typedef __attribute__((ext_vector_type(4))) float f32x4;

#define GAS __attribute__((address_space(1)))
#define LAS __attribute__((address_space(3)))

__device__ __forceinline__ u16 f2b(float f) {
  union { float f; u32 i; } v; v.f = f;
  return (u16)((v.i + 0x7fffu + ((v.i >> 16) & 1u)) >> 16);
}

__device__ __forceinline__ void gl_lds(const u16* g, u16* l) {
  __builtin_amdgcn_global_load_lds((const GAS void*)g, (LAS void*)l, 16, 0, 0);
}

// ---------------- f32 -> bf16 convert (prev_hidden) ----------------
__global__ void cvt_f32_bf16(const float* __restrict__ in, u16* __restrict__ outp) {
  const size_t i = ((size_t)blockIdx.x * 256 + threadIdx.x) * 4;
  const float4 v = *(const float4*)&in[i];
  ushort4 o;
  o.x = f2b(v.x); o.y = f2b(v.y); o.z = f2b(v.z); o.w = f2b(v.w);
  *(ushort4*)&outp[i] = o;
}

// --------- weight transpose, f32 row-major R x C -> bf16 C x R ---------
__device__ __forceinline__ void transpose_body(const float* __restrict__ in,
                                               u16* __restrict__ outp,
                                               int R, int C, int c0, int r0) {
  __shared__ u16 t[32][33];
  const int x = threadIdx.x, y = threadIdx.y;
  #pragma unroll
  for (int i = 0; i < 32; i += 8)
    t[y + i][x] = f2b(in[(size_t)(r0 + y + i) * C + (c0 + x)]);
  __syncthreads();
  #pragma unroll
  for (int i = 0; i < 32; i += 8)
    outp[(size_t)(c0 + y + i) * R + (r0 + x)] = t[x][y + i];
}

__global__ void transpose_f32_bf16(const float* __restrict__ in, u16* __restrict__ outp,
                                   int R, int C) {
  transpose_body(in, outp, R, C, blockIdx.x * 32, blockIdx.y * 32);
}

// merged W_O{1..4} transpose: z selects matrix; all R=448; C in {448,256}
__global__ void transpose_wo(const float* __restrict__ w1, const float* __restrict__ w2,
                             const float* __restrict__ w3, const float* __restrict__ w4,
                             u16* __restrict__ o1, u16* __restrict__ o2,
                             u16* __restrict__ o3, u16* __restrict__ o4) {
  const int z = blockIdx.z;
  const float* in = (z == 0) ? w1 : (z == 1) ? w2 : (z == 2) ? w3 : w4;
  u16* outp = (z == 0) ? o1 : (z == 1) ? o2 : (z == 2) ? o3 : o4;
  const int C = (z & 1) ? 256 : 448;
  const int c0 = blockIdx.x * 32;
  if (c0 >= C) return;
  transpose_body(in, outp, 448, C, c0, blockIdx.y * 32);
}

// ---------------- fused gate kernel: 512 thr, 8 waves (2m x 4n) -------------
// Block tile 64 rows x (128 j-cols x 3 gates = 384). Wave tile 32 x 96
// (jj = 2*wn+jj2, s in 0..2; nn = jj*3+s, 24 B-tiles of 16x32 = 1KB each).
// A: global->reg, 2 b128 loads/wave/iter (rows m0+wm*32+mt*16+l16, col q*8).
// B: LDS 3-ring, 24KB/buf, XOR bank swizzle (pre-swizzled src col sc, read
// seg qs). Staging: unit u = 3*wave+i (i<3) = nn; 3 gl_lds/wave/iter UNIFORM.
// vmcnt(3) pre-barrier: stage(t) has >=3 newer loads issued; in-order vmem
// retirement => <=3 outstanding implies stage(t) done.
__global__ __launch_bounds__(512, 4)
void gate_kernel(const u16* __restrict__ phb, const u16* __restrict__ wrt,
                 const float* __restrict__ phf,
                 const float* __restrict__ y2, const float* __restrict__ cc,
                 const float* __restrict__ wic, const float* __restrict__ wif,
                 const float* __restrict__ bu, const float* __restrict__ br,
                 const float* __restrict__ be,
                 float* __restrict__ houtf, u16* __restrict__ hb) {
  __shared__ u16 Bl[3][12288];          // 3 x 24KB
  __shared__ float rowy[3 * 64];
  const int tid = threadIdx.x;
  const int lane = tid & 63, wave = tid >> 6;   // wave 0..7
  const int f = blockIdx.x;
  const int xcd = f & 7, l = f >> 3;            // 448 blocks per XCD
  const int m0 = (xcd * 64 + l / 7) * 64;       // j-inner: A-tile L2 reuse
  const int j0 = (l % 7) * 128;
  if (tid < 64) {
    const int r = m0 + tid;
    rowy[tid]      = y2[2 * r];
    rowy[64 + tid] = y2[2 * r + 1];
    rowy[128 + tid] = cc[r];
    asm volatile("s_waitcnt lgkmcnt(0)" ::: "memory");
  }
  const int wm = wave & 1, wn = wave >> 1;      // 2m x 4n
  const int q = lane >> 4, l16 = lane & 15;
  const int qs = q ^ ((l16 >> 1) & 3);          // bank-swizzled read segment
  const int sr = lane >> 2;
  const int sc = ((lane & 3) ^ ((lane >> 3) & 3)) * 8;  // pre-swizzled src col

  // A base: per-lane row m0+wm*32+l16 (+mt*16), col q*8 (+t*32)
  const u16* ag = phb + (size_t)(m0 + wm * 32 + l16) * 896 + q * 8;

  // B staging: 3 units/wave; unit u = 3*wave+i = nn (0..23); s = nn%3, jj = nn/3
  const u16* gs[3]; int lo[3];
  #pragma unroll
  for (int i = 0; i < 3; ++i) {
    const int nn = 3 * wave + i;
    const int s = nn % 3, jj = nn / 3;
    gs[i] = wrt + (size_t)(s * 896 + j0 + jj * 16 + sr) * 896 + sc;
    lo[i] = nn * 512;
  }

  f32x4 acc[2][3][2];   // [jj2][s][mt]
  {
    const f32x4 z = {0.f, 0.f, 0.f, 0.f};
    #pragma unroll
    for (int a = 0; a < 2; ++a)
      #pragma unroll
      for (int s = 0; s < 3; ++s)
        #pragma unroll
        for (int m = 0; m < 2; ++m)
          acc[a][s][m] = z;
  }

  auto stage = [&](int t_) {
    u16* base = &Bl[t_ % 3][0];
    const int koff = t_ * 32;
    #pragma unroll
    for (int i = 0; i < 3; ++i) gl_lds(gs[i] + koff, base + lo[i]);
  };

  stage(0); stage(1);
  for (int t = 0; t < 28; ++t) {
    asm volatile("s_waitcnt vmcnt(3)" ::: "memory");
    __builtin_amdgcn_s_barrier();
    __builtin_amdgcn_sched_barrier(0);
    bf16x8 af[2];
    #pragma unroll
    for (int mt = 0; mt < 2; ++mt)
      af[mt] = *(const bf16x8*)(ag + (size_t)mt * 16 * 896 + t * 32);
    stage(t + 2 < 27 ? t + 2 : 27);   // tail re-stages same bytes: benign
    const u16* Sb = &Bl[t % 3][0];
    #pragma unroll
    for (int jj2 = 0; jj2 < 2; ++jj2)
      #pragma unroll
      for (int s = 0; s < 3; ++s) {
        const int nn = (2 * wn + jj2) * 3 + s;
        const bf16x8 bf_ = *(const bf16x8*)&Sb[nn * 512 + l16 * 32 + qs * 8];
        #pragma unroll
        for (int mt = 0; mt < 2; ++mt)
          acc[jj2][s][mt] = __builtin_amdgcn_mfma_f32_16x16x32_bf16(
              af[mt], bf_, acc[jj2][s][mt], 0, 0, 0);
      }
  }
  asm volatile("s_waitcnt vmcnt(0)" ::: "memory");  // drain before LDS realloc

  // ---- fused epilogue: u, r, e, h; each thread owns its (u,r,e) triple
  #pragma unroll
  for (int jj2 = 0; jj2 < 2; ++jj2) {
    const int j = j0 + (2 * wn + jj2) * 16 + l16;
    float wu0, wu1, wu2, wr0, wr1, wr2, we0, we1, we2;
    if (j < 448) {
      wu0 = wic[j];       wu1 = wic[1344 + j];       wu2 = 0.f;
      wr0 = wic[448 + j]; wr1 = wic[1792 + j];       wr2 = 0.f;
      we0 = wic[896 + j]; we1 = wic[2240 + j];       we2 = 0.f;
    } else {
      const int jf = j - 448;
      wu0 = wif[jf];       wu1 = wif[1344 + jf]; wu2 = wif[2688 + jf];
      wr0 = wif[448 + jf]; wr1 = wif[1792 + jf]; wr2 = wif[3136 + jf];
      we0 = wif[896 + jf]; we1 = wif[2240 + jf]; we2 = wif[3584 + jf];
    }
    const float bju = bu[j], bjr = br[j], bje = be[j];
    #pragma unroll
    for (int mt = 0; mt < 2; ++mt) {
      const int rl = wm * 32 + mt * 16 + q * 4;
      #pragma unroll
      for (int i = 0; i < 4; ++i) {
        const float y0 = rowy[rl + i], y1 = rowy[64 + rl + i], yc = rowy[128 + rl + i];
        const float gu = acc[jj2][0][mt][i] + y0 * wu0 + y1 * wu1 + yc * wu2 + bju;
        const float gr = acc[jj2][1][mt][i] + y0 * wr0 + y1 * wr1 + yc * wr2 + bjr;
        const float uu = 1.f / (1.f + __expf(-gu));
        const float rg = 1.f / (1.f + __expf(-gr));
        const float ev = tanhf(rg * acc[jj2][2][mt][i] +
                               y0 * we0 + y1 * we1 + yc * we2 + bje);
        const size_t grow = (size_t)(m0 + rl + i);
        const float phv = phf[grow * 896 + j];
        const float h = uu * phv + (1.f - uu) * ev;
        houtf[grow * 896 + j] = h;
        hb[grow * 896 + j] = f2b(h);
      }
    }
  }
}

// ------------- 128x128 MLP GEMM, K=448 (NT=7, BK=64), A->reg, B->LDS -------
// 4 waves 2m x 2n; wave 64x64; acc[4][4]. 16 staging units = 4/wave.
__device__ __forceinline__ void mlp_gemm(const u16* __restrict__ A, int lda,
                                         const u16* __restrict__ BT, int ldb,
                                         u16 (&Bl)[3][8192],
                                         int wave, int lane, f32x4 (&acc)[4][4]) {
  const int wm = wave & 1, wn = wave >> 1;
  const int q = lane >> 4, l16 = lane & 15;
  const int qs = q ^ ((l16 >> 1) & 3);
  const int sr = lane >> 2;
  const int sc = ((lane & 3) ^ ((lane >> 3) & 3)) * 8;
  const u16* ag = A + (size_t)(wm * 64 + l16) * lda + q * 8;
  const u16* gs[4]; int lo[4];
  #pragma unroll
  for (int i = 0; i < 4; ++i) {
    const int u = 4 * wave + i, ntile = u >> 1, kh = u & 1;
    gs[i] = BT + (size_t)(ntile * 16 + sr) * ldb + (kh * 32 + sc);
    lo[i] = u * 512;
  }
  auto stage = [&](int t_) {
    u16* base = &Bl[t_ % 3][0];
    const int koff = t_ * 64;
    #pragma unroll
    for (int i = 0; i < 4; ++i) gl_lds(gs[i] + koff, base + lo[i]);
  };
  stage(0); stage(1);
  for (int t = 0; t < 7; ++t) {
    asm volatile("s_waitcnt vmcnt(4)" ::: "memory");
    __builtin_amdgcn_s_barrier();
    __builtin_amdgcn_sched_barrier(0);
    bf16x8 af[2][4];
    #pragma unroll
    for (int kh = 0; kh < 2; ++kh)
      #pragma unroll
      for (int mt = 0; mt < 4; ++mt)
        af[kh][mt] = *(const bf16x8*)(ag + (size_t)mt * 16 * lda + t * 64 + kh * 32);
    stage(t + 2 < 6 ? t + 2 : 6);     // tail re-stages same bytes: benign
    const u16* Sb = &Bl[t % 3][0];
    #pragma unroll
    for (int kh = 0; kh < 2; ++kh) {
      bf16x8 bf_[4];
      #pragma unroll
      for (int nf = 0; nf < 4; ++nf)
        bf_[nf] = *(const bf16x8*)&Sb[(wn * 4 + nf) * 1024 + kh * 512 + l16 * 32 + qs * 8];
      #pragma unroll
      for (int nf = 0; nf < 4; ++nf)
        #pragma unroll
        for (int mt = 0; mt < 4; ++mt)
          acc[mt][nf] = __builtin_amdgcn_mfma_f32_16x16x32_bf16(
              af[kh][mt], bf_[nf], acc[mt][nf], 0, 0, 0);
    }
  }
  asm volatile("s_waitcnt vmcnt(0)" ::: "memory");  // drain before LDS realloc
}

__device__ __forceinline__ void zero_acc(f32x4 (&acc)[4][4]) {
  const f32x4 z = {0.f, 0.f, 0.f, 0.f};
  #pragma unroll
  for (int mt = 0; mt < 4; ++mt)
    #pragma unroll
    for (int nt = 0; nt < 4; ++nt)
      acc[mt][nt] = z;
}

// ---------------- stage 1: T_z = relu(h_z @ W_O{1,3} + b), bf16 out ----------
// grid 2048 = 8 xcd * 64 mz_local * 4 j (swizzled; last j tile: B rows >=448
// read garbage in-ws bytes; write masked by j<448).
__global__ __launch_bounds__(256, 3)
void stage1_kernel(const u16* __restrict__ hb, const u16* __restrict__ w1t,
                   const u16* __restrict__ w3t, const float* __restrict__ b1,
                   const float* __restrict__ b3, u16* __restrict__ tc,
                   u16* __restrict__ tf) {
  __shared__ u16 Bl[3][8192];
  const int tid = threadIdx.x, lane = tid & 63, wave = tid >> 6;
  const int f = blockIdx.x;
  const int xcd = f & 7, l = f >> 3;          // l in [0,256)
  const int mz = xcd * 64 + (l >> 2);         // (m,z) pair, 512 total
  const int z = mz >> 8;
  const int m0 = (mz & 255) * 128, n0 = (l & 3) * 128;
  const u16* A = hb + (size_t)m0 * 896 + z * 448;
  const u16* BT = (z ? w3t : w1t) + (size_t)n0 * 448;
  const float* bias = z ? b3 : b1;
  u16* T = z ? tf : tc;
  const int wm = wave & 1, wn = wave >> 1, q = lane >> 4, l16 = lane & 15;
  f32x4 acc[4][4];
  zero_acc(acc);
  mlp_gemm(A, 896, BT, 448, Bl, wave, lane, acc);
  #pragma unroll
  for (int nf = 0; nf < 4; ++nf) {
    const int j = n0 + wn * 64 + nf * 16 + l16;
    if (j < 448) {
      const float bv = bias[j];
      #pragma unroll
      for (int mt = 0; mt < 4; ++mt)
        #pragma unroll
        for (int i = 0; i < 4; ++i) {
          const size_t row = (size_t)(m0 + wm * 64 + mt * 16 + q * 4 + i);
          T[row * 448 + j] = f2b(fmaxf(acc[mt][nf][i] + bv, 0.f));
        }
    }
  }
}

// ---------------- stage 2: out_z = T_z @ W_O{2,4} + b, f32 out ----------------
// grid 1024 = 8 xcd * 64 mz_local * 2 j (swizzled)
__global__ __launch_bounds__(256, 3)
void stage2_kernel(const u16* __restrict__ tc, const u16* __restrict__ tf,
                   const u16* __restrict__ w2t, const u16* __restrict__ w4t,
                   const float* __restrict__ b2_, const float* __restrict__ b4,
                   float* __restrict__ out) {
  __shared__ u16 Bl[3][8192];
  const int tid = threadIdx.x, lane = tid & 63, wave = tid >> 6;
  const int f = blockIdx.x;
  const int xcd = f & 7, l = f >> 3;          // l in [0,128)
  const int mz = xcd * 64 + (l >> 1);
  const int z = mz >> 8;
  const int m0 = (mz & 255) * 128, n0 = (l & 1) * 128;
  const u16* A = (z ? tf : tc) + (size_t)m0 * 448;
  const u16* BT = (z ? w4t : w2t) + (size_t)n0 * 448;
  const float* bias = z ? b4 : b2_;
  float* O = out + (size_t)z * 32768 * 256;
  const int wm = wave & 1, wn = wave >> 1, q = lane >> 4, l16 = lane & 15;
  f32x4 acc[4][4];
  zero_acc(acc);
  mlp_gemm(A, 448, BT, 448, Bl, wave, lane, acc);
  #pragma unroll
  for (int nf = 0; nf < 4; ++nf) {
    const int j = n0 + wn * 64 + nf * 16 + l16;  // always < 256
    const float bv = bias[j];
    #pragma unroll
    for (int mt = 0; mt < 4; ++mt)
      #pragma unroll
      for (int i = 0; i < 4; ++i) {
        const size_t row = (size_t)(m0 + wm * 64 + mt * 16 + q * 4 + i);
        O[row * 256 + j] = acc[mt][nf][i] + bv;
      }
  }
}

// ---------------- host launch ----------------
extern "C" void kernel_launch(void* const* d_in, const int* in_sizes, int n_in,
                              void* d_out, int out_size, void* d_ws, size_t ws_size,
                              hipStream_t stream) {
  const float* y2   = (const float*)d_in[0];   // prev_y (B,2)
  const float* ph   = (const float*)d_in[1];   // prev_hidden (B,896)
  const float* cc   = (const float*)d_in[2];   // current_coarse (B,1)
  const float* W_R  = (const float*)d_in[3];   // (896, 2688)
  const float* W_Ic = (const float*)d_in[4];   // (2, 1344)
  const float* W_If = (const float*)d_in[5];   // (3, 1344)
  const float* W_O1 = (const float*)d_in[6];   // (448,448)
  const float* b_O1 = (const float*)d_in[7];
  const float* W_O2 = (const float*)d_in[8];   // (448,256)
  const float* b_O2 = (const float*)d_in[9];
  const float* W_O3 = (const float*)d_in[10];
  const float* b_O3 = (const float*)d_in[11];
  const float* W_O4 = (const float*)d_in[12];
  const float* b_O4 = (const float*)d_in[13];
  const float* bu   = (const float*)d_in[14];
  const float* br   = (const float*)d_in[15];
  const float* be   = (const float*)d_in[16];
  float* out = (float*)d_out;
  u16* ws  = (u16*)d_ws;

  // workspace layout (u16 elements), all offsets multiples of 8 (16B aligned)
  u16* WRT = ws;                               // 2688*896      = 2,408,448
  u16* W1T = WRT + (size_t)2688 * 896;         // 448*448
  u16* W2T = W1T + 448 * 448;                  // 256*448
  u16* W3T = W2T + 256 * 448;                  // 448*448
  u16* W4T = W3T + 448 * 448;                  // 256*448
  u16* phb = W4T + 256 * 448;                  // 32768*896 bf16
  u16* hb  = phb + (size_t)32768 * 896;        // 32768*896 bf16
  // Tc/Tf alias phb (dead after gate_kernel): 2 x 32768*448
  u16* Tc  = phb;
  u16* Tf  = phb + (size_t)32768 * 448;
  float* hidf = out + (size_t)2 * 32768 * 256; // hidden (output 2) in d_out

  dim3 tb(32, 8);
  cvt_f32_bf16<<<28672, 256, 0, stream>>>(ph, phb);
  transpose_f32_bf16<<<dim3(2688 / 32, 896 / 32), tb, 0, stream>>>(W_R, WRT, 896, 2688);
  transpose_wo<<<dim3(14, 14, 4), tb, 0, stream>>>(W_O1, W_O2, W_O3, W_O4,
                                                   W1T, W2T, W3T, W4T);

  gate_kernel<<<3584, 512, 0, stream>>>(phb, WRT, ph, y2, cc, W_Ic, W_If,
                                        bu, br, be, hidf, hb);
  stage1_kernel<<<2048, 256, 0, stream>>>(hb, W1T, W3T, b_O1, b_O3, Tc, Tf);
  stage2_kernel<<<1024, 256, 0, stream>>>(Tc, Tf, W2T, W4T, b_O2, b_O4, out);
}

// Round 7
// 738.292 us; speedup vs baseline: 1.8211x; 1.0801x over previous
//
#include <hip/hip_runtime.h>

// WaveRNN cell, MI355X. B=32768 H=896 S=448 Q=256.
// R7 changes vs R6 (which was latency-bound: A-frag global loads issued after
// the barrier and consumed immediately -> ~full L2 latency exposed on every
// one of 28 iters; nothing saturated: HBM 16%, Mfma 16%, VALU 27%):
//  - gate: A-frag REGISTER PREFETCH one iter ahead. body(t) issues A loads
//    for t+1; MFMAs use the pair loaded at t-1. Loop unrolled x2 with named
//    afA/afB (no runtime-indexed reg arrays). vmcnt(3) at top of iter forces
//    af(t) + stage(t) complete (3 newer stage loads outstanding); af(t) had a
//    full iteration of cover. 5 vmem ops/body keeps compiler static counts
//    branch-free.
//  - stage1/stage2: reverted VERBATIM to R1's gemm_tile_k structure
//    (single-buffer, 2 barriers/iter, (256,2)) - best measured rest (278us);
//    the A-to-reg mlp_gemm variants had the same naked-latency disease.

typedef unsigned short u16;
typedef unsigned int u32;
typedef __attribute__((ext_vector_type(8))) short bf16x8;
typedef __attribute__((ext_vector_type(4))) float f32x4;

#define GAS __attribute__((address_space(1)))
#define LAS __attribute__((address_space(3)))

__device__ __forceinline__ u16 f2b(float f) {
  union { float f; u32 i; } v; v.f = f;
  return (u16)((v.i + 0x7fffu + ((v.i >> 16) & 1u)) >> 16);
}

__device__ __forceinline__ void gl_lds(const u16* g, u16* l) {
  __builtin_amdgcn_global_load_lds((const GAS void*)g, (LAS void*)l, 16, 0, 0);
}

// ---------------- f32 -> bf16 convert (prev_hidden) ----------------
__global__ void cvt_f32_bf16(const float* __restrict__ in, u16* __restrict__ outp) {
  const size_t i = ((size_t)blockIdx.x * 256 + threadIdx.x) * 4;
  const float4 v = *(const float4*)&in[i];
  ushort4 o;
  o.x = f2b(v.x); o.y = f2b(v.y); o.z = f2b(v.z); o.w = f2b(v.w);
  *(ushort4*)&outp[i] = o;
}

// --------- weight transpose, f32 row-major R x C -> bf16 C x R ---------
__device__ __forceinline__ void transpose_body(const float* __restrict__ in,
                                               u16* __restrict__ outp,
                                               int R, int C, int c0, int r0) {
  __shared__ u16 t[32][33];
  const int x = threadIdx.x, y = threadIdx.y;
  #pragma unroll
  for (int i = 0; i < 32; i += 8)
    t[y + i][x] = f2b(in[(size_t)(r0 + y + i) * C + (c0 + x)]);
  __syncthreads();
  #pragma unroll
  for (int i = 0; i < 32; i += 8)
    outp[(size_t)(c0 + y + i) * R + (r0 + x)] = t[x][y + i];
}

__global__ void transpose_f32_bf16(const float* __restrict__ in, u16* __restrict__ outp,
                                   int R, int C) {
  transpose_body(in, outp, R, C, blockIdx.x * 32, blockIdx.y * 32);
}

// merged W_O{1..4} transpose: z selects matrix; all R=448; C in {448,256}
__global__ void transpose_wo(const float* __restrict__ w1, const float* __restrict__ w2,
                             const float* __restrict__ w3, const float* __restrict__ w4,
                             u16* __restrict__ o1, u16* __restrict__ o2,
                             u16* __restrict__ o3, u16* __restrict__ o4) {
  const int z = blockIdx.z;
  const float* in = (z == 0) ? w1 : (z == 1) ? w2 : (z == 2) ? w3 : w4;
  u16* outp = (z == 0) ? o1 : (z == 1) ? o2 : (z == 2) ? o3 : o4;
  const int C = (z & 1) ? 256 : 448;
  const int c0 = blockIdx.x * 32;
  if (c0 >= C) return;
  transpose_body(in, outp, 448, C, c0, blockIdx.y * 32);
}

// ------------- 128x128 tile K-loop (R1 verbatim: single-buffer) -------------
// 4 waves as 2x2 grid of 64x64; BK=32; acc[4][4] f32x4. (stage1/stage2)
__device__ __forceinline__ void gemm_tile_k(const u16* __restrict__ A, int lda,
                                            const u16* __restrict__ BT, int ldb,
                                            int K, u16* Al, u16* Bl,
                                            int wave, int lane, f32x4 (&acc)[4][4]) {
  const int wm = wave & 1, wn = wave >> 1;
  const int q = lane >> 4, l16 = lane & 15;
  const int sr = lane >> 2;          // staging sub-row 0..15
  const int sc = (lane & 3) * 8;     // staging col offset (elements)
  for (int k0 = 0; k0 < K; k0 += 32) {
    #pragma unroll
    for (int i = 0; i < 2; ++i) {
      const int rr = wave * 32 + i * 16;  // wave-uniform row base
      gl_lds(A + (size_t)(rr + sr) * lda + (k0 + sc), &Al[rr * 32]);
      gl_lds(BT + (size_t)(rr + sr) * ldb + (k0 + sc), &Bl[rr * 32]);
    }
    __syncthreads();
    bf16x8 af[4], bfr[4];
    #pragma unroll
    for (int t = 0; t < 4; ++t) {
      af[t]  = *(const bf16x8*)&Al[(wm * 64 + t * 16 + l16) * 32 + q * 8];
      bfr[t] = *(const bf16x8*)&Bl[(wn * 64 + t * 16 + l16) * 32 + q * 8];
    }
    #pragma unroll
    for (int mt = 0; mt < 4; ++mt)
      #pragma unroll
      for (int nt = 0; nt < 4; ++nt)
        acc[mt][nt] = __builtin_amdgcn_mfma_f32_16x16x32_bf16(af[mt], bfr[nt],
                                                              acc[mt][nt], 0, 0, 0);
    __syncthreads();
  }
}

__device__ __forceinline__ void zero_acc(f32x4 (&acc)[4][4]) {
  const f32x4 z = {0.f, 0.f, 0.f, 0.f};
  #pragma unroll
  for (int mt = 0; mt < 4; ++mt)
    #pragma unroll
    for (int nt = 0; nt < 4; ++nt)
      acc[mt][nt] = z;
}

// ---------------- fused gate kernel: 512 thr, 8 waves (2m x 4n) -------------
// Block tile 64 rows x (128 j-cols x 3 gates = 384). Wave tile 32 x 96
// (jj = 2*wn+jj2, s in 0..2; nn = jj*3+s, 24 B-tiles of 16x32 = 1KB each).
// A: global->REGISTER, prefetched ONE ITER AHEAD (afA/afB ping-pong, x2
// unrolled loop so all reg indices are static).
// B: LDS 3-ring, 24KB/buf, XOR bank swizzle. 3 gl_lds/wave/iter UNIFORM.
// Per body: 5 vmem ops [af(t+1) x2, stage(t+2) x3]. Top-of-iter vmcnt(3):
// newer-than-af(t) = 3 stage loads => af(t) AND stage(t) complete.
__global__ __launch_bounds__(512, 4)
void gate_kernel(const u16* __restrict__ phb, const u16* __restrict__ wrt,
                 const float* __restrict__ phf,
                 const float* __restrict__ y2, const float* __restrict__ cc,
                 const float* __restrict__ wic, const float* __restrict__ wif,
                 const float* __restrict__ bu, const float* __restrict__ br,
                 const float* __restrict__ be,
                 float* __restrict__ houtf, u16* __restrict__ hb) {
  __shared__ u16 Bl[3][12288];          // 3 x 24KB
  __shared__ float rowy[3 * 64];
  const int tid = threadIdx.x;
  const int lane = tid & 63, wave = tid >> 6;   // wave 0..7
  const int f = blockIdx.x;
  const int xcd = f & 7, l = f >> 3;            // 448 blocks per XCD
  const int m0 = (xcd * 64 + l / 7) * 64;       // j-inner: A-tile L2 reuse
  const int j0 = (l % 7) * 128;
  if (tid < 64) {
    const int r = m0 + tid;
    rowy[tid]      = y2[2 * r];
    rowy[64 + tid] = y2[2 * r + 1];
    rowy[128 + tid] = cc[r];
    asm volatile("s_waitcnt lgkmcnt(0)" ::: "memory");
  }
  const int wm = wave & 1, wn = wave >> 1;      // 2m x 4n
  const int q = lane >> 4, l16 = lane & 15;
  const int qs = q ^ ((l16 >> 1) & 3);          // bank-swizzled read segment
  const int sr = lane >> 2;
  const int sc = ((lane & 3) ^ ((lane >> 3) & 3)) * 8;  // pre-swizzled src col

  // A base: per-lane row m0+wm*32+l16 (+mt*16), col q*8 (+t*32)
  const u16* ag = phb + (size_t)(m0 + wm * 32 + l16) * 896 + q * 8;

  // B staging: 3 units/wave; unit u = 3*wave+i = nn (0..23); s = nn%3, jj = nn/3
  const u16* gs[3]; int lo[3];
  #pragma unroll
  for (int i = 0; i < 3; ++i) {
    const int nn = 3 * wave + i;
    const int s = nn % 3, jj = nn / 3;
    gs[i] = wrt + (size_t)(s * 896 + j0 + jj * 16 + sr) * 896 + sc;
    lo[i] = nn * 512;
  }

  f32x4 acc[2][3][2];   // [jj2][s][mt]
  {
    const f32x4 z = {0.f, 0.f, 0.f, 0.f};
    #pragma unroll
    for (int a = 0; a < 2; ++a)
      #pragma unroll
      for (int s = 0; s < 3; ++s)
        #pragma unroll
        for (int m = 0; m < 2; ++m)
          acc[a][s][m] = z;
  }

  auto stage = [&](int t_) {
    u16* base = &Bl[t_ % 3][0];
    const int koff = t_ * 32;
    #pragma unroll
    for (int i = 0; i < 3; ++i) gl_lds(gs[i] + koff, base + lo[i]);
  };

  // prologue: stage(0), stage(1), A(0) into afA
  stage(0); stage(1);
  bf16x8 afA[2], afB[2];
  afA[0] = *(const bf16x8*)(ag);
  afA[1] = *(const bf16x8*)(ag + (size_t)16 * 896);

  #define GATE_BODY(T, AFU, AFL)                                               \
    {                                                                          \
      const int t = (T);                                                       \
      asm volatile("s_waitcnt vmcnt(3)" ::: "memory");                         \
      __builtin_amdgcn_s_barrier();                                            \
      __builtin_amdgcn_sched_barrier(0);                                       \
      const int tn = (t + 1 < 28) ? t + 1 : 27;                                \
      AFL[0] = *(const bf16x8*)(ag + tn * 32);                                 \
      AFL[1] = *(const bf16x8*)(ag + (size_t)16 * 896 + tn * 32);              \
      stage(t + 2 < 27 ? t + 2 : 27);                                          \
      const u16* Sb = &Bl[t % 3][0];                                           \
      _Pragma("unroll")                                                        \
      for (int jj2 = 0; jj2 < 2; ++jj2)                                        \
        _Pragma("unroll")                                                      \
        for (int s = 0; s < 3; ++s) {                                          \
          const int nn = (2 * wn + jj2) * 3 + s;                               \
          const bf16x8 bf_ = *(const bf16x8*)&Sb[nn * 512 + l16 * 32 + qs * 8];\
          _Pragma("unroll")                                                    \
          for (int mt = 0; mt < 2; ++mt)                                       \
            acc[jj2][s][mt] = __builtin_amdgcn_mfma_f32_16x16x32_bf16(         \
                AFU[mt], bf_, acc[jj2][s][mt], 0, 0, 0);                       \
        }                                                                      \
    }

  for (int tt = 0; tt < 14; ++tt) {
    GATE_BODY(2 * tt,     afA, afB)   // use A(t) in afA, load A(t+1) into afB
    GATE_BODY(2 * tt + 1, afB, afA)   // use afB, load into afA
  }
  #undef GATE_BODY
  asm volatile("s_waitcnt vmcnt(0)" ::: "memory");  // drain before LDS realloc

  // ---- fused epilogue: u, r, e, h; each thread owns its (u,r,e) triple
  #pragma unroll
  for (int jj2 = 0; jj2 < 2; ++jj2) {
    const int j = j0 + (2 * wn + jj2) * 16 + l16;
    float wu0, wu1, wu2, wr0, wr1, wr2, we0, we1, we2;
    if (j < 448) {
      wu0 = wic[j];       wu1 = wic[1344 + j];       wu2 = 0.f;
      wr0 = wic[448 + j]; wr1 = wic[1792 + j];       wr2 = 0.f;
      we0 = wic[896 + j]; we1 = wic[2240 + j];       we2 = 0.f;
    } else {
      const int jf = j - 448;
      wu0 = wif[jf];       wu1 = wif[1344 + jf]; wu2 = wif[2688 + jf];
      wr0 = wif[448 + jf]; wr1 = wif[1792 + jf]; wr2 = wif[3136 + jf];
      we0 = wif[896 + jf]; we1 = wif[2240 + jf]; we2 = wif[3584 + jf];
    }
    const float bju = bu[j], bjr = br[j], bje = be[j];
    #pragma unroll
    for (int mt = 0; mt < 2; ++mt) {
      const int rl = wm * 32 + mt * 16 + q * 4;
      #pragma unroll
      for (int i = 0; i < 4; ++i) {
        const float y0 = rowy[rl + i], y1 = rowy[64 + rl + i], yc = rowy[128 + rl + i];
        const float gu = acc[jj2][0][mt][i] + y0 * wu0 + y1 * wu1 + yc * wu2 + bju;
        const float gr = acc[jj2][1][mt][i] + y0 * wr0 + y1 * wr1 + yc * wr2 + bjr;
        const float uu = 1.f / (1.f + __expf(-gu));
        const float rg = 1.f / (1.f + __expf(-gr));
        const float ev = tanhf(rg * acc[jj2][2][mt][i] +
                               y0 * we0 + y1 * we1 + yc * we2 + bje);
        const size_t grow = (size_t)(m0 + rl + i);
        const float phv = phf[grow * 896 + j];
        const float h = uu * phv + (1.f - uu) * ev;
        houtf[grow * 896 + j] = h;
        hb[grow * 896 + j] = f2b(h);
      }
    }
  }
}

// ---------------- stage 1: T_z = relu(h_z @ W_O{1,3} + b), bf16 out ----------
// grid 2048 = 8 xcd * 64 mz_local * 4 j (swizzled; last j tile: rows >=448 of
// BT read garbage in-ws bytes; write masked by j<448).
__global__ __launch_bounds__(256, 2)
void stage1_kernel(const u16* __restrict__ hb, const u16* __restrict__ w1t,
                   const u16* __restrict__ w3t, const float* __restrict__ b1,
                   const float* __restrict__ b3, u16* __restrict__ tc,
                   u16* __restrict__ tf) {
  __shared__ u16 Al[128 * 32];
  __shared__ u16 Bl[128 * 32];
  const int tid = threadIdx.x, lane = tid & 63, wave = tid >> 6;
  const int f = blockIdx.x;
  const int xcd = f & 7, l = f >> 3;          // l in [0,256)
  const int mz = xcd * 64 + (l >> 2);         // (m,z) pair, 512 total
  const int z = mz >> 8;
  const int m0 = (mz & 255) * 128, n0 = (l & 3) * 128;
  const u16* A = hb + (size_t)m0 * 896 + z * 448;
  const u16* BT = (z ? w3t : w1t) + (size_t)n0 * 448;
  const float* bias = z ? b3 : b1;
  u16* T = z ? tf : tc;
  const int wm = wave & 1, wn = wave >> 1, q = lane >> 4, l16 = lane & 15;
  f32x4 acc[4][4];
  zero_acc(acc);
  gemm_tile_k(A, 896, BT, 448, 448, Al, Bl, wave, lane, acc);
  #pragma unroll
  for (int nt = 0; nt < 4; ++nt) {
    const int j = n0 + wn * 64 + nt * 16 + l16;
    if (j < 448) {
      const float bv = bias[j];
      #pragma unroll
      for (int mt = 0; mt < 4; ++mt)
        #pragma unroll
        for (int i = 0; i < 4; ++i) {
          const size_t row = (size_t)(m0 + wm * 64 + mt * 16 + q * 4 + i);
          T[row * 448 + j] = f2b(fmaxf(acc[mt][nt][i] + bv, 0.f));
        }
    }
  }
}

// ---------------- stage 2: out_z = T_z @ W_O{2,4} + b, f32 out ----------------
// grid 1024 = 8 xcd * 64 mz_local * 2 j (swizzled)
__global__ __launch_bounds__(256, 2)
void stage2_kernel(const u16* __restrict__ tc, const u16* __restrict__ tf,
                   const u16* __restrict__ w2t, const u16* __restrict__ w4t,
                   const float* __restrict__ b2_, const float* __restrict__ b4,
                   float* __restrict__ out) {
  __shared__ u16 Al[128 * 32];
  __shared__ u16 Bl[128 * 32];
  const int tid = threadIdx.x, lane = tid & 63, wave = tid >> 6;
  const int f = blockIdx.x;
  const int xcd = f & 7, l = f >> 3;          // l in [0,128)
  const int mz = xcd * 64 + (l >> 1);
  const int z = mz >> 8;
  const int m0 = (mz & 255) * 128, n0 = (l & 1) * 128;
  const u16* A = (z ? tf : tc) + (size_t)m0 * 448;
  const u16* BT = (z ? w4t : w2t) + (size_t)n0 * 448;
  const float* bias = z ? b4 : b2_;
  float* O = out + (size_t)z * 32768 * 256;
  const int wm = wave & 1, wn = wave >> 1, q = lane >> 4, l16 = lane & 15;
  f32x4 acc[4][4];
  zero_acc(acc);
  gemm_tile_k(A, 448, BT, 448, 448, Al, Bl, wave, lane, acc);
  #pragma unroll
  for (int nt = 0; nt < 4; ++nt) {
    const int j = n0 + wn * 64 + nt * 16 + l16;  // always < 256
    const float bv = bias[j];
    #pragma unroll
    for (int mt = 0; mt < 4; ++mt)
      #pragma unroll
      for (int i = 0; i < 4; ++i) {
        const size_t row = (size_t)(m0 + wm * 64 + mt * 16 + q * 4 + i);
        O[row * 256 + j] = acc[mt][nt][i] + bv;
      }
  }
}

// ---------------- host launch ----------------
extern "C" void kernel_launch(void* const* d_in, const int* in_sizes, int n_in,
                              void* d_out, int out_size, void* d_ws, size_t ws_size,
                              hipStream_t stream) {
  const float* y2   = (const float*)d_in[0];   // prev_y (B,2)
  const float* ph   = (const float*)d_in[1];   // prev_hidden (B,896)
  const float* cc   = (const float*)d_in[2];   // current_coarse (B,1)
  const float* W_R  = (const float*)d_in[3];   // (896, 2688)
  const float* W_Ic = (const float*)d_in[4];   // (2, 1344)
  const float* W_If = (const float*)d_in[5];   // (3, 1344)
  const float* W_O1 = (const float*)d_in[6];   // (448,448)
  const float* b_O1 = (const float*)d_in[7];
  const float* W_O2 = (const float*)d_in[8];   // (448,256)
  const float* b_O2 = (const float*)d_in[9];
  const float* W_O3 = (const float*)d_in[10];
  const float* b_O3 = (const float*)d_in[11];
  const float* W_O4 = (const float*)d_in[12];
  const float* b_O4 = (const float*)d_in[13];
  const float* bu   = (const float*)d_in[14];
  const float* br   = (const float*)d_in[15];
  const float* be   = (const float*)d_in[16];
  float* out = (float*)d_out;
  u16* ws  = (u16*)d_ws;

  // workspace layout (u16 elements), all offsets multiples of 8 (16B aligned)
  u16* WRT = ws;                               // 2688*896      = 2,408,448
  u16* W1T = WRT + (size_t)2688 * 896;         // 448*448
  u16* W2T = W1T + 448 * 448;                  // 256*448
  u16* W3T = W2T + 256 * 448;                  // 448*448
  u16* W4T = W3T + 448 * 448;                  // 256*448
  u16* phb = W4T + 256 * 448;                  // 32768*896 bf16
  u16* hb  = phb + (size_t)32768 * 896;        // 32768*896 bf16
  // Tc/Tf alias phb (dead after gate_kernel): 2 x 32768*448
  u16* Tc  = phb;
  u16* Tf  = phb + (size_t)32768 * 448;
  float* hidf = out + (size_t)2 * 32768 * 256; // hidden (output 2) in d_out

  dim3 tb(32, 8);
  cvt_f32_bf16<<<28672, 256, 0, stream>>>(ph, phb);
  transpose_f32_bf16<<<dim3(2688 / 32, 896 / 32), tb, 0, stream>>>(W_R, WRT, 896, 2688);
  transpose_wo<<<dim3(14, 14, 4), tb, 0, stream>>>(W_O1, W_O2, W_O3, W_O4,
                                                   W1T, W2T, W3T, W4T);

  gate_kernel<<<3584, 512, 0, stream>>>(phb, WRT, ph, y2, cc, W_Ic, W_If,
                                        bu, br, be, hidf, hb);
  stage1_kernel<<<2048, 256, 0, stream>>>(hb, W1T, W3T, b_O1, b_O3, Tc, Tf);
  stage2_kernel<<<1024, 256, 0, stream>>>(Tc, Tf, W2T, W4T, b_O2, b_O4, out);
}

// Round 8
// 610.327 us; speedup vs baseline: 2.2029x; 1.2097x over previous
//
#include <hip/hip_runtime.h>

// WaveRNN cell, MI355X. B=32768 H=896 S=448 Q=256.
// R8 changes:
//  - gate_kernel: REVERTED VERBATIM to R4 (best measured: 270us, MfmaUtil
//    26.5%, conflicts 0). The R5-R7 B-only/A-direct family was structurally
//    worse (16% MfmaUtil; A re-reads just moved LDS traffic to VMEM).
//  - stage1/stage2: R4 recipe ported. 512-thr blocks, 8 waves 2m x 4n (wave
//    64x32, acc[4][2]=32 regs), LDS buf = A 8KB + B 8KB = 16 x 1KB units =
//    2 gl_lds/wave/iter uniform, 3-buf ring 48KB -> 2 blocks/CU, XOR bank
//    swizzle (R4-proven), vmcnt(2) + ONE barrier per iter, NT=14. Replaces
//    R1's drain structure (vmcnt(0) + 2 barriers/iter) that held the rest at
//    ~300-360us for 41 GF.

typedef unsigned short u16;
typedef unsigned int u32;
typedef __attribute__((ext_vector_type(8))) short bf16x8;
typedef __attribute__((ext_vector_type(4))) float f32x4;

#define GAS __attribute__((address_space(1)))
#define LAS __attribute__((address_space(3)))

__device__ __forceinline__ u16 f2b(float f) {
  union { float f; u32 i; } v; v.f = f;
  return (u16)((v.i + 0x7fffu + ((v.i >> 16) & 1u)) >> 16);
}

__device__ __forceinline__ void gl_lds(const u16* g, u16* l) {
  __builtin_amdgcn_global_load_lds((const GAS void*)g, (LAS void*)l, 16, 0, 0);
}

// ---------------- f32 -> bf16 convert (prev_hidden) ----------------
__global__ void cvt_f32_bf16(const float* __restrict__ in, u16* __restrict__ outp) {
  const size_t i = ((size_t)blockIdx.x * 256 + threadIdx.x) * 4;
  const float4 v = *(const float4*)&in[i];
  ushort4 o;
  o.x = f2b(v.x); o.y = f2b(v.y); o.z = f2b(v.z); o.w = f2b(v.w);
  *(ushort4*)&outp[i] = o;
}

// --------- weight transpose, f32 row-major R x C -> bf16 C x R ---------
__device__ __forceinline__ void transpose_body(const float* __restrict__ in,
                                               u16* __restrict__ outp,
                                               int R, int C, int c0, int r0) {
  __shared__ u16 t[32][33];
  const int x = threadIdx.x, y = threadIdx.y;
  #pragma unroll
  for (int i = 0; i < 32; i += 8)
    t[y + i][x] = f2b(in[(size_t)(r0 + y + i) * C + (c0 + x)]);
  __syncthreads();
  #pragma unroll
  for (int i = 0; i < 32; i += 8)
    outp[(size_t)(c0 + y + i) * R + (r0 + x)] = t[x][y + i];
}

__global__ void transpose_f32_bf16(const float* __restrict__ in, u16* __restrict__ outp,
                                   int R, int C) {
  transpose_body(in, outp, R, C, blockIdx.x * 32, blockIdx.y * 32);
}

// merged W_O{1..4} transpose: z selects matrix; all R=448; C in {448,256}
__global__ void transpose_wo(const float* __restrict__ w1, const float* __restrict__ w2,
                             const float* __restrict__ w3, const float* __restrict__ w4,
                             u16* __restrict__ o1, u16* __restrict__ o2,
                             u16* __restrict__ o3, u16* __restrict__ o4) {
  const int z = blockIdx.z;
  const float* in = (z == 0) ? w1 : (z == 1) ? w2 : (z == 2) ? w3 : w4;
  u16* outp = (z == 0) ? o1 : (z == 1) ? o2 : (z == 2) ? o3 : o4;
  const int C = (z & 1) ? 256 : 448;
  const int c0 = blockIdx.x * 32;
  if (c0 >= C) return;
  transpose_body(in, outp, 448, C, c0, blockIdx.y * 32);
}

// ---------------- fused gate kernel (R4 verbatim): 1024 thr, 16 waves -------
// Block tile: 128 rows x (3 gates x 128 cols), gate-interleaved column tiles:
// nn = jj*3 + s. Wave (wm=wave&3, wn=wave>>2): rows wm*32+mt*16, col tiles
// nn=(2*wn+jj2)*3+s. LDS per buf: A 128x32 at [0..4096), B 24 tiles of 16x32
// at [4096+nn*512). Staging: 32 gl_lds/iter, unit u=2*wave+{0,1}; ring of 3,
// prefetch t+2, s_waitcnt vmcnt(2), one s_barrier per iter. XOR bank swizzle
// (pre-swizzled src col sc, swizzled read seg qs).
__global__ __launch_bounds__(1024, 4)
void gate_kernel(const u16* __restrict__ phb, const u16* __restrict__ wrt,
                 const float* __restrict__ phf,
                 const float* __restrict__ y2, const float* __restrict__ cc,
                 const float* __restrict__ wic, const float* __restrict__ wif,
                 const float* __restrict__ bu, const float* __restrict__ br,
                 const float* __restrict__ be,
                 float* __restrict__ houtf, u16* __restrict__ hb) {
  __shared__ u16 Sl[3][16384];
  __shared__ float rowy[3 * 128];
  const int tid = threadIdx.x;
  const int lane = tid & 63, wave = tid >> 6;
  const int f = blockIdx.x;
  const int xcd = f & 7, l = f >> 3;            // 224 blocks per XCD
  const int m0 = (xcd * 32 + l / 7) * 128;      // j-inner: 7 j-siblings
  const int j0 = (l % 7) * 128;                 // adjacent -> A L2 reuse
  if (tid < 128) {
    const int r = m0 + tid;
    rowy[tid]       = y2[2 * r];
    rowy[128 + tid] = y2[2 * r + 1];
    rowy[256 + tid] = cc[r];
    asm volatile("s_waitcnt lgkmcnt(0)" ::: "memory");
  }
  const int wm = wave & 3, wn = wave >> 2;
  const int q = lane >> 4, l16 = lane & 15;
  const int qs = q ^ ((l16 >> 1) & 3);          // bank-swizzled read segment
  const int sr = lane >> 2;
  const int sc = ((lane & 3) ^ ((lane >> 3) & 3)) * 8;  // pre-swizzled src col

  // per-wave staging units
  const int u0 = 2 * wave, u1 = u0 + 1;
  const u16* g0; const u16* g1; int lo0, lo1;
  if (u0 < 8) { g0 = phb + (size_t)(m0 + u0 * 16 + sr) * 896 + sc; lo0 = u0 * 512; }
  else { const int nn = u0 - 8, jj = nn / 3, s = nn % 3;
         g0 = wrt + (size_t)(s * 896 + j0 + jj * 16 + sr) * 896 + sc;
         lo0 = 4096 + nn * 512; }
  if (u1 < 8) { g1 = phb + (size_t)(m0 + u1 * 16 + sr) * 896 + sc; lo1 = u1 * 512; }
  else { const int nn = u1 - 8, jj = nn / 3, s = nn % 3;
         g1 = wrt + (size_t)(s * 896 + j0 + jj * 16 + sr) * 896 + sc;
         lo1 = 4096 + nn * 512; }

  f32x4 acc[2][3][2];   // [jj2][s][mt]
  {
    const f32x4 z = {0.f, 0.f, 0.f, 0.f};
    #pragma unroll
    for (int a = 0; a < 2; ++a)
      #pragma unroll
      for (int s = 0; s < 3; ++s)
        #pragma unroll
        for (int m = 0; m < 2; ++m)
          acc[a][s][m] = z;
  }

  auto stage = [&](int t_) {
    const int b_ = t_ % 3;
    const int k_ = t_ * 32;
    gl_lds(g0 + k_, &Sl[b_][lo0]);
    gl_lds(g1 + k_, &Sl[b_][lo1]);
  };

  stage(0);
  stage(1);
  for (int t = 0; t < 28; ++t) {
    if (t < 27) asm volatile("s_waitcnt vmcnt(2)" ::: "memory");
    else        asm volatile("s_waitcnt vmcnt(0)" ::: "memory");
    __builtin_amdgcn_s_barrier();
    __builtin_amdgcn_sched_barrier(0);
    const u16* Sb = Sl[t % 3];
    bf16x8 af[2];
    #pragma unroll
    for (int mt = 0; mt < 2; ++mt)
      af[mt] = *(const bf16x8*)&Sb[(wm * 32 + mt * 16 + l16) * 32 + qs * 8];
    #pragma unroll
    for (int jj2 = 0; jj2 < 2; ++jj2)
      #pragma unroll
      for (int s = 0; s < 3; ++s) {
        const int nn = (2 * wn + jj2) * 3 + s;
        const bf16x8 bf_ = *(const bf16x8*)&Sb[4096 + nn * 512 + l16 * 32 + qs * 8];
        #pragma unroll
        for (int mt = 0; mt < 2; ++mt)
          acc[jj2][s][mt] = __builtin_amdgcn_mfma_f32_16x16x32_bf16(
              af[mt], bf_, acc[jj2][s][mt], 0, 0, 0);
      }
    if (t + 2 < 28) stage(t + 2);
  }

  // ---- fused epilogue: u, r, e, h; each thread owns its (u,r,e) triple
  #pragma unroll
  for (int jj2 = 0; jj2 < 2; ++jj2) {
    const int j = j0 + (2 * wn + jj2) * 16 + l16;
    float wu0, wu1, wu2, wr0, wr1, wr2, we0, we1, we2;
    if (j < 448) {
      wu0 = wic[j];       wu1 = wic[1344 + j];       wu2 = 0.f;
      wr0 = wic[448 + j]; wr1 = wic[1792 + j];       wr2 = 0.f;
      we0 = wic[896 + j]; we1 = wic[2240 + j];       we2 = 0.f;
    } else {
      const int jf = j - 448;
      wu0 = wif[jf];       wu1 = wif[1344 + jf]; wu2 = wif[2688 + jf];
      wr0 = wif[448 + jf]; wr1 = wif[1792 + jf]; wr2 = wif[3136 + jf];
      we0 = wif[896 + jf]; we1 = wif[2240 + jf]; we2 = wif[3584 + jf];
    }
    const float bju = bu[j], bjr = br[j], bje = be[j];
    #pragma unroll
    for (int mt = 0; mt < 2; ++mt) {
      const int rl = wm * 32 + mt * 16 + q * 4;
      #pragma unroll
      for (int i = 0; i < 4; ++i) {
        const float y0 = rowy[rl + i], y1 = rowy[128 + rl + i], yc = rowy[256 + rl + i];
        const float gu = acc[jj2][0][mt][i] + y0 * wu0 + y1 * wu1 + yc * wu2 + bju;
        const float gr = acc[jj2][1][mt][i] + y0 * wr0 + y1 * wr1 + yc * wr2 + bjr;
        const float uu = 1.f / (1.f + __expf(-gu));
        const float rg = 1.f / (1.f + __expf(-gr));
        const float ev = tanhf(rg * acc[jj2][2][mt][i] +
                               y0 * we0 + y1 * we1 + yc * we2 + bje);
        const size_t grow = (size_t)(m0 + rl + i);
        const float phv = phf[grow * 896 + j];
        const float h = uu * phv + (1.f - uu) * ev;
        houtf[grow * 896 + j] = h;
        hb[grow * 896 + j] = f2b(h);
      }
    }
  }
}

// ------------- stage GEMM (R4 recipe): 128x128, K=448, BK=32, NT=14 ---------
// 512 thr, 8 waves 2m x 4n; wave 64x32; acc[4][2]. LDS buf 16KB = A[128x32]
// at [0,4096) + B[128x32] at [4096,8192); 16 units of 1KB = 2/wave uniform.
// 3-buf ring, prefetch t+2, vmcnt(2) + ONE barrier/iter. XOR bank swizzle.
__device__ __forceinline__ void stage_gemm(const u16* __restrict__ A, int lda,
                                           const u16* __restrict__ BT, int ldb,
                                           u16 (&Bl)[3][8192],
                                           int wave, int lane, f32x4 (&acc)[4][2]) {
  const int wm = wave & 1, wn = wave >> 1;
  const int q = lane >> 4, l16 = lane & 15;
  const int qs = q ^ ((l16 >> 1) & 3);
  const int sr = lane >> 2;
  const int sc = ((lane & 3) ^ ((lane >> 3) & 3)) * 8;
  // staging units: u = 2*wave+i; u<8 -> A rows u*16; u>=8 -> B rows (u-8)*16.
  // LDS offset = u*512 in both cases (B lands at 4096+).
  const u16* gs0; const u16* gs1; int lo0, lo1;
  {
    const int u = 2 * wave;
    gs0 = (u < 8) ? A + (size_t)(u * 16 + sr) * lda + sc
                  : BT + (size_t)((u - 8) * 16 + sr) * ldb + sc;
    lo0 = u * 512;
  }
  {
    const int u = 2 * wave + 1;
    gs1 = (u < 8) ? A + (size_t)(u * 16 + sr) * lda + sc
                  : BT + (size_t)((u - 8) * 16 + sr) * ldb + sc;
    lo1 = u * 512;
  }
  auto stage = [&](int t_) {
    u16* base = &Bl[t_ % 3][0];
    const int koff = t_ * 32;
    gl_lds(gs0 + koff, base + lo0);
    gl_lds(gs1 + koff, base + lo1);
  };
  stage(0); stage(1);
  for (int t = 0; t < 14; ++t) {
    if (t < 13) asm volatile("s_waitcnt vmcnt(2)" ::: "memory");
    else        asm volatile("s_waitcnt vmcnt(0)" ::: "memory");
    __builtin_amdgcn_s_barrier();
    __builtin_amdgcn_sched_barrier(0);
    const u16* Sb = &Bl[t % 3][0];
    bf16x8 af[4], bfr[2];
    #pragma unroll
    for (int mt = 0; mt < 4; ++mt)
      af[mt] = *(const bf16x8*)&Sb[(wm * 64 + mt * 16 + l16) * 32 + qs * 8];
    #pragma unroll
    for (int nt = 0; nt < 2; ++nt)
      bfr[nt] = *(const bf16x8*)&Sb[4096 + (wn * 32 + nt * 16 + l16) * 32 + qs * 8];
    #pragma unroll
    for (int mt = 0; mt < 4; ++mt)
      #pragma unroll
      for (int nt = 0; nt < 2; ++nt)
        acc[mt][nt] = __builtin_amdgcn_mfma_f32_16x16x32_bf16(af[mt], bfr[nt],
                                                              acc[mt][nt], 0, 0, 0);
    if (t + 2 < 14) stage(t + 2);
  }
}

// ---------------- stage 1: T_z = relu(h_z @ W_O{1,3} + b), bf16 out ----------
// grid 2048 = 8 xcd * 64 mz_local * 4 j (swizzled; last j tile: rows >=448 of
// BT read garbage in-ws bytes; write masked by j<448).
__global__ __launch_bounds__(512, 4)
void stage1_kernel(const u16* __restrict__ hb, const u16* __restrict__ w1t,
                   const u16* __restrict__ w3t, const float* __restrict__ b1,
                   const float* __restrict__ b3, u16* __restrict__ tc,
                   u16* __restrict__ tf) {
  __shared__ u16 Bl[3][8192];
  const int tid = threadIdx.x, lane = tid & 63, wave = tid >> 6;
  const int f = blockIdx.x;
  const int xcd = f & 7, l = f >> 3;          // l in [0,256)
  const int mz = xcd * 64 + (l >> 2);         // (m,z) pair, 512 total
  const int z = mz >> 8;
  const int m0 = (mz & 255) * 128, n0 = (l & 3) * 128;
  const u16* A = hb + (size_t)m0 * 896 + z * 448;
  const u16* BT = (z ? w3t : w1t) + (size_t)n0 * 448;
  const float* bias = z ? b3 : b1;
  u16* T = z ? tf : tc;
  const int wm = wave & 1, wn = wave >> 1, q = lane >> 4, l16 = lane & 15;
  f32x4 acc[4][2];
  {
    const f32x4 zz = {0.f, 0.f, 0.f, 0.f};
    #pragma unroll
    for (int mt = 0; mt < 4; ++mt)
      #pragma unroll
      for (int nt = 0; nt < 2; ++nt)
        acc[mt][nt] = zz;
  }
  stage_gemm(A, 896, BT, 448, Bl, wave, lane, acc);
  #pragma unroll
  for (int nt = 0; nt < 2; ++nt) {
    const int j = n0 + wn * 32 + nt * 16 + l16;
    if (j < 448) {
      const float bv = bias[j];
      #pragma unroll
      for (int mt = 0; mt < 4; ++mt)
        #pragma unroll
        for (int i = 0; i < 4; ++i) {
          const size_t row = (size_t)(m0 + wm * 64 + mt * 16 + q * 4 + i);
          T[row * 448 + j] = f2b(fmaxf(acc[mt][nt][i] + bv, 0.f));
        }
    }
  }
}

// ---------------- stage 2: out_z = T_z @ W_O{2,4} + b, f32 out ----------------
// grid 1024 = 8 xcd * 64 mz_local * 2 j (swizzled)
__global__ __launch_bounds__(512, 4)
void stage2_kernel(const u16* __restrict__ tc, const u16* __restrict__ tf,
                   const u16* __restrict__ w2t, const u16* __restrict__ w4t,
                   const float* __restrict__ b2_, const float* __restrict__ b4,
                   float* __restrict__ out) {
  __shared__ u16 Bl[3][8192];
  const int tid = threadIdx.x, lane = tid & 63, wave = tid >> 6;
  const int f = blockIdx.x;
  const int xcd = f & 7, l = f >> 3;          // l in [0,128)
  const int mz = xcd * 64 + (l >> 1);
  const int z = mz >> 8;
  const int m0 = (mz & 255) * 128, n0 = (l & 1) * 128;
  const u16* A = (z ? tf : tc) + (size_t)m0 * 448;
  const u16* BT = (z ? w4t : w2t) + (size_t)n0 * 448;
  const float* bias = z ? b4 : b2_;
  float* O = out + (size_t)z * 32768 * 256;
  const int wm = wave & 1, wn = wave >> 1, q = lane >> 4, l16 = lane & 15;
  f32x4 acc[4][2];
  {
    const f32x4 zz = {0.f, 0.f, 0.f, 0.f};
    #pragma unroll
    for (int mt = 0; mt < 4; ++mt)
      #pragma unroll
      for (int nt = 0; nt < 2; ++nt)
        acc[mt][nt] = zz;
  }
  stage_gemm(A, 448, BT, 448, Bl, wave, lane, acc);
  #pragma unroll
  for (int nt = 0; nt < 2; ++nt) {
    const int j = n0 + wn * 32 + nt * 16 + l16;  // always < 256
    const float bv = bias[j];
    #pragma unroll
    for (int mt = 0; mt < 4; ++mt)
      #pragma unroll
      for (int i = 0; i < 4; ++i) {
        const size_t row = (size_t)(m0 + wm * 64 + mt * 16 + q * 4 + i);
        O[row * 256 + j] = acc[mt][nt][i] + bv;
      }
  }
}

// ---------------- host launch ----------------
extern "C" void kernel_launch(void* const* d_in, const int* in_sizes, int n_in,
                              void* d_out, int out_size, void* d_ws, size_t ws_size,
                              hipStream_t stream) {
  const float* y2   = (const float*)d_in[0];   // prev_y (B,2)
  const float* ph   = (const float*)d_in[1];   // prev_hidden (B,896)
  const float* cc   = (const float*)d_in[2];   // current_coarse (B,1)
  const float* W_R  = (const float*)d_in[3];   // (896, 2688)
  const float* W_Ic = (const float*)d_in[4];   // (2, 1344)
  const float* W_If = (const float*)d_in[5];   // (3, 1344)
  const float* W_O1 = (const float*)d_in[6];   // (448,448)
  const float* b_O1 = (const float*)d_in[7];
  const float* W_O2 = (const float*)d_in[8];   // (448,256)
  const float* b_O2 = (const float*)d_in[9];
  const float* W_O3 = (const float*)d_in[10];
  const float* b_O3 = (const float*)d_in[11];
  const float* W_O4 = (const float*)d_in[12];
  const float* b_O4 = (const float*)d_in[13];
  const float* bu   = (const float*)d_in[14];
  const float* br   = (const float*)d_in[15];
  const float* be   = (const float*)d_in[16];
  float* out = (float*)d_out;
  u16* ws  = (u16*)d_ws;

  // workspace layout (u16 elements), all offsets multiples of 8 (16B aligned)
  u16* WRT = ws;                               // 2688*896      = 2,408,448
  u16* W1T = WRT + (size_t)2688 * 896;         // 448*448
  u16* W2T = W1T + 448 * 448;                  // 256*448
  u16* W3T = W2T + 256 * 448;                  // 448*448
  u16* W4T = W3T + 448 * 448;                  // 256*448
  u16* phb = W4T + 256 * 448;                  // 32768*896 bf16
  u16* hb  = phb + (size_t)32768 * 896;        // 32768*896 bf16
  // Tc/Tf alias phb (dead after gate_kernel): 2 x 32768*448
  u16* Tc  = phb;
  u16* Tf  = phb + (size_t)32768 * 448;
  float* hidf = out + (size_t)2 * 32768 * 256; // hidden (output 2) in d_out

  dim3 tb(32, 8);
  cvt_f32_bf16<<<28672, 256, 0, stream>>>(ph, phb);
  transpose_f32_bf16<<<dim3(2688 / 32, 896 / 32), tb, 0, stream>>>(W_R, WRT, 896, 2688);
  transpose_wo<<<dim3(14, 14, 4), tb, 0, stream>>>(W_O1, W_O2, W_O3, W_O4,
                                                   W1T, W2T, W3T, W4T);

  gate_kernel<<<1792, 1024, 0, stream>>>(phb, WRT, ph, y2, cc, W_Ic, W_If,
                                         bu, br, be, hidf, hb);
  stage1_kernel<<<2048, 512, 0, stream>>>(hb, W1T, W3T, b_O1, b_O3, Tc, Tf);
  stage2_kernel<<<1024, 512, 0, stream>>>(Tc, Tf, W2T, W4T, b_O2, b_O4, out);
}